// Round 1
// baseline (92.696 us; speedup 1.0000x reference)
//
#include <hip/hip_runtime.h>
#include <stdint.h>

#define NE 64        // real experts
#define E  65        // kernel uses num_experts + 1
#define BLK 128      // block_size
#define G 2048       // wave-granular subchunks (T/G = 4096 tokens per wave)
#define WPB 4        // waves per 256-thread block
#define THREADS 256

// emulate match_any over 64 lanes for expert ids in [0,64): 6 ballots
__device__ __forceinline__ unsigned long long match_any6(int e) {
    unsigned long long m = ~0ull;
#pragma unroll
    for (int b = 0; b < 6; ++b) {
        unsigned long long bal = __ballot((e >> b) & 1);
        m &= ((e >> b) & 1) ? bal : ~bal;
    }
    return m;
}

__global__ void k_fill(int* __restrict__ sorted, int m, int fillv) {
    long long i = ((long long)blockIdx.x * THREADS + threadIdx.x) * 4;
    if (i + 4 <= m) {
        *(int4*)(sorted + i) = make_int4(fillv, fillv, fillv, fillv);
    } else {
        for (; i < m; ++i) sorted[i] = fillv;
    }
}

// per-wave histogram of its 4096-token subchunk -> cnt[g][e]
__global__ void k_hist(const int* __restrict__ topk, int* __restrict__ cnt, int sub) {
    __shared__ int hist[WPB][E];
    const int tid = threadIdx.x, w = tid >> 6, lane = tid & 63;
    const int g = blockIdx.x * WPB + w;
    for (int e = lane; e < E; e += 64) hist[w][e] = 0;   // wave-private row: no sync
    const long long start = (long long)g * sub;
    const unsigned long long lt = ((unsigned long long)1 << lane) - 1ull;
    const int iters = sub >> 6;
    for (int it = 0; it < iters; ++it) {
        int e = topk[start + it * 64 + lane];
        unsigned long long m = match_any6(e);
        if ((m & lt) == 0ull) hist[w][e] += __popcll(m);  // leader lane per expert group
    }
    for (int e = lane; e < E; e += 64) cnt[g * E + e] = hist[w][e];
}

// per-expert exclusive prefix over the G subchunks (in place); counts[e] = total
__global__ void k_scan(int* __restrict__ cnt, int* __restrict__ counts) {
    const int e = blockIdx.x;          // 65 blocks
    const int tid = threadIdx.x;       // 256
    const int PER = G / THREADS;       // 8
    int v[PER];
    int s = 0;
#pragma unroll
    for (int j = 0; j < PER; ++j) { v[j] = cnt[(tid * PER + j) * E + e]; s += v[j]; }
    __shared__ int sc[THREADS];
    sc[tid] = s;
    __syncthreads();
    for (int d = 1; d < THREADS; d <<= 1) {   // Hillis-Steele inclusive scan
        int t = (tid >= d) ? sc[tid - d] : 0;
        __syncthreads();
        sc[tid] += t;
        __syncthreads();
    }
    int excl = (tid == 0) ? 0 : sc[tid - 1];
    if (tid == THREADS - 1) counts[e] = sc[THREADS - 1];
#pragma unroll
    for (int j = 0; j < PER; ++j) { int t = v[j]; cnt[(tid * PER + j) * E + e] = excl; excl += t; }
}

// off_pad / cum_pad / num_tokens_post_pad from per-expert counts
__global__ void k_off(const int* __restrict__ counts, int* __restrict__ off_pad,
                      int* __restrict__ cum_pad, int* __restrict__ npp) {
    __shared__ int c[E];
    int tid = threadIdx.x;
    if (tid < E) c[tid] = counts[tid];
    __syncthreads();
    if (tid == 0) {
        int run = 0;
        for (int e = 0; e < E; ++e) {
            int p = (c[e] + BLK - 1) & ~(BLK - 1);
            off_pad[e] = run;
            run += p;
            cum_pad[e] = run;
        }
        *npp = run;
    }
}

__global__ void k_eids(const int* __restrict__ cum_pad, int* __restrict__ eids, int nb) {
    __shared__ int cp[E];
    int tid = threadIdx.x;
    if (tid < E) cp[tid] = cum_pad[tid];
    __syncthreads();
    int b = blockIdx.x * THREADS + tid;
    if (b < nb) {
        int bstart = b * BLK;
        int r = 0;
        if (bstart < cp[E - 1]) {
            int lo = 0, hi = E;                 // first idx with cp[idx] > bstart
            while (lo < hi) { int mid = (lo + hi) >> 1; if (cp[mid] <= bstart) lo = mid + 1; else hi = mid; }
            r = lo;
        }
        eids[b] = r;
    }
}

// stable scatter: wave-private running offsets, zero barriers in main loop
__global__ void k_scatter(const int* __restrict__ topk, const int* __restrict__ base,
                          const int* __restrict__ off_pad, int* __restrict__ sorted, int sub) {
    __shared__ int run[WPB][E];
    const int tid = threadIdx.x, w = tid >> 6, lane = tid & 63;
    const int g = blockIdx.x * WPB + w;
    for (int e = lane; e < E; e += 64) run[w][e] = off_pad[e] + base[g * E + e];
    const long long start = (long long)g * sub;
    const unsigned long long lt = ((unsigned long long)1 << lane) - 1ull;
    const int iters = sub >> 6;
    for (int it = 0; it < iters; ++it) {
        int idx = (int)(start + it * 64 + lane);
        int e = topk[idx];
        unsigned long long m = match_any6(e);
        int r = __popcll(m & lt);          // stable rank among same-expert lanes
        int b = run[w][e];                 // wave-lockstep read-before-write
        sorted[b + r] = idx;
        if ((m & lt) == 0ull) run[w][e] = b + __popcll(m);
    }
}

extern "C" void kernel_launch(void* const* d_in, const int* in_sizes, int n_in,
                              void* d_out, int out_size, void* d_ws, size_t ws_size,
                              hipStream_t stream) {
    const int* topk = (const int*)d_in[0];
    const int T = in_sizes[0];                       // 8388608 flat routed tokens
    const int M = T + E * (BLK - 1);                 // max_num_tokens_padded
    const int nb = M / BLK;                          // max_num_m_blocks

    int* out = (int*)d_out;
    int* sorted = out;
    int* expert_ids = out + M;
    int* npp = out + M + nb;

    int* cnt     = (int*)d_ws;                       // G*E
    int* counts  = cnt + (size_t)G * E;              // E
    int* off_pad = counts + E;                       // E
    int* cum_pad = off_pad + E;                      // E

    const int sub = T / G;                           // 4096

    const int grid_fill = (int)(((long long)(M + 3) / 4 + THREADS - 1) / THREADS);
    k_fill<<<grid_fill, THREADS, 0, stream>>>(sorted, M, T);
    k_hist<<<G / WPB, THREADS, 0, stream>>>(topk, cnt, sub);
    k_scan<<<E, THREADS, 0, stream>>>(cnt, counts);
    k_off<<<1, 128, 0, stream>>>(counts, off_pad, cum_pad, npp);
    k_eids<<<(nb + THREADS - 1) / THREADS, THREADS, 0, stream>>>(cum_pad, expert_ids, nb);
    k_scatter<<<G / WPB, THREADS, 0, stream>>>(topk, cnt, off_pad, sorted, sub);
}

// Round 2
// 64.120 us; speedup vs baseline: 1.4457x; 1.4457x over previous
//
#include <hip/hip_runtime.h>
#include <stdint.h>

#define E  65        // num_experts + 1
#define BLK 128      // block_size
#define WPB 4        // waves per 256-thread block
#define THREADS 256
#define CHUNK 64     // subchunks per scan chunk
#define MAXNC 128    // max chunks (G=8192)

// emulate match_any over 64 lanes for expert ids in [0,64): 6 ballots
__device__ __forceinline__ unsigned long long match_any6(int e) {
    unsigned long long m = ~0ull;
#pragma unroll
    for (int b = 0; b < 6; ++b) {
        unsigned long long bal = __ballot((e >> b) & 1);
        m &= ((e >> b) & 1) ? bal : ~bal;
    }
    return m;
}

// per-wave histogram via LDS atomics (no cross-lane ballots, no RMW chain)
__global__ void __launch_bounds__(THREADS) k_hist(const int* __restrict__ topk,
                                                  int* __restrict__ cnt, int sub) {
    __shared__ int hist[WPB][E];
    const int tid = threadIdx.x, w = tid >> 6, lane = tid & 63;
    const int g = blockIdx.x * WPB + w;
    for (int e = lane; e < E; e += 64) hist[w][e] = 0;   // wave-private row
    const int start = g * sub;
    const int iters = sub >> 8;                          // 256 tokens per iter
    for (int it = 0; it < iters; ++it) {
        int4 v = *(const int4*)(topk + start + it * 256 + lane * 4);
        atomicAdd(&hist[w][v.x], 1);
        atomicAdd(&hist[w][v.y], 1);
        atomicAdd(&hist[w][v.z], 1);
        atomicAdd(&hist[w][v.w], 1);
    }
    for (int e = lane; e < E; e += 64) cnt[g * E + e] = hist[w][e];
}

// level-1: exclusive scan of cnt over the 64 subchunks of each chunk (in place),
// chunk totals -> ctot[c][e]
__global__ void k_scan1(int* __restrict__ cnt, int* __restrict__ ctot) {
    __shared__ int buf[CHUNK * E];
    const int c = blockIdx.x, tid = threadIdx.x;
    for (int i = tid; i < CHUNK * E; i += THREADS) buf[i] = cnt[c * CHUNK * E + i];
    __syncthreads();
    if (tid < E) {
        int acc = 0;
#pragma unroll 8
        for (int j = 0; j < CHUNK; ++j) {
            int old = buf[j * E + tid];
            buf[j * E + tid] = acc;
            acc += old;
        }
        ctot[c * E + tid] = acc;
    }
    __syncthreads();
    for (int i = tid; i < CHUNK * E; i += THREADS) cnt[c * CHUNK * E + i] = buf[i];
}

// level-2: exclusive scan of ctot over chunks (in place), per-expert totals,
// then off_pad / cum_pad / num_tokens_post_pad
__global__ void k_scan2(int* __restrict__ ctot, int* __restrict__ counts,
                        int* __restrict__ off_pad, int* __restrict__ cum_pad,
                        int* __restrict__ npp, int nc) {
    __shared__ int buf[MAXNC * E];
    const int tid = threadIdx.x;
    for (int i = tid; i < nc * E; i += THREADS) buf[i] = ctot[i];
    __syncthreads();
    if (tid < E) {
        int acc = 0;
        for (int c = 0; c < nc; ++c) {
            int old = buf[c * E + tid];
            buf[c * E + tid] = acc;
            acc += old;
        }
        counts[tid] = acc;
    }
    __syncthreads();
    for (int i = tid; i < nc * E; i += THREADS) ctot[i] = buf[i];
    if (tid == 0) {
        int run = 0;
        for (int e = 0; e < E; ++e) {
            int p = (counts[e] + BLK - 1) & ~(BLK - 1);
            off_pad[e] = run;
            run += p;
            cum_pad[e] = run;
        }
        *npp = run;
    }
}

__global__ void k_eids(const int* __restrict__ cum_pad, int* __restrict__ eids, int nb) {
    __shared__ int cp[E];
    int tid = threadIdx.x;
    if (tid < E) cp[tid] = cum_pad[tid];
    __syncthreads();
    int b = blockIdx.x * THREADS + tid;
    if (b < nb) {
        int bstart = b * BLK;
        int r = 0;
        if (bstart < cp[E - 1]) {
            int lo = 0, hi = E;
            while (lo < hi) { int mid = (lo + hi) >> 1; if (cp[mid] <= bstart) lo = mid + 1; else hi = mid; }
            r = lo;
        }
        eids[b] = r;
    }
}

// fill only the pad slots (per-expert gap) and the tail beyond cum_pad[E-1]
__global__ void k_gapfill(const int* __restrict__ counts, const int* __restrict__ off_pad,
                          const int* __restrict__ cum_pad, int* __restrict__ sorted,
                          int m, int fillv) {
    const int b = blockIdx.x, tid = threadIdx.x;
    if (b < E) {
        int c = counts[b];
        int p = (c + BLK - 1) & ~(BLK - 1);
        int len = p - c;                      // <= 127
        if (tid < len) sorted[off_pad[b] + c + tid] = fillv;
    } else {
        int total = cum_pad[E - 1];
        int i = total + (b - E) * THREADS + tid;
        if (i < m) sorted[i] = fillv;
    }
}

// stable scatter: wave-private running offsets, 4-group prefetch, zero barriers
__global__ void __launch_bounds__(THREADS) k_scatter(const int* __restrict__ topk,
                          const int* __restrict__ base, const int* __restrict__ ctot,
                          const int* __restrict__ off_pad, int* __restrict__ sorted, int sub) {
    __shared__ int run[WPB][E];
    const int tid = threadIdx.x, w = tid >> 6, lane = tid & 63;
    const int g = blockIdx.x * WPB + w;
    const int chunk = g >> 6;
    for (int e = lane; e < E; e += 64)
        run[w][e] = off_pad[e] + ctot[chunk * E + e] + base[g * E + e];
    const int start = g * sub;
    const unsigned long long lt = ((unsigned long long)1 << lane) - 1ull;
    const int iters = sub >> 8;                           // 256 tokens per iter
    for (int it = 0; it < iters; ++it) {
        const int gb = start + it * 256;
        int t0 = topk[gb + lane];
        int t1 = topk[gb + 64 + lane];
        int t2 = topk[gb + 128 + lane];
        int t3 = topk[gb + 192 + lane];
#pragma unroll
        for (int p = 0; p < 4; ++p) {
            int e = (p == 0) ? t0 : (p == 1) ? t1 : (p == 2) ? t2 : t3;
            unsigned long long m = match_any6(e);
            int r = __popcll(m & lt);
            int b = run[w][e];
            sorted[b + r] = gb + p * 64 + lane;
            if ((m & lt) == 0ull) run[w][e] = b + __popcll(m);
        }
    }
}

extern "C" void kernel_launch(void* const* d_in, const int* in_sizes, int n_in,
                              void* d_out, int out_size, void* d_ws, size_t ws_size,
                              hipStream_t stream) {
    const int* topk = (const int*)d_in[0];
    const int T = in_sizes[0];                       // 8388608
    const int M = T + E * (BLK - 1);
    const int nb = M / BLK;

    int* out = (int*)d_out;
    int* sorted = out;
    int* expert_ids = out + M;
    int* npp = out + M + nb;

    // pick largest G that fits workspace
    int G = 8192;
    while (G > 2048) {
        size_t need = ((size_t)G * E + (size_t)(G / CHUNK) * E + 3 * E) * sizeof(int);
        if (need <= ws_size) break;
        G >>= 1;
    }
    const int NC = G / CHUNK;
    const int sub = T / G;

    int* cnt     = (int*)d_ws;                       // G*E
    int* ctot    = cnt + (size_t)G * E;              // NC*E
    int* counts  = ctot + (size_t)NC * E;            // E
    int* off_pad = counts + E;                       // E
    int* cum_pad = off_pad + E;                      // E

    k_hist<<<G / WPB, THREADS, 0, stream>>>(topk, cnt, sub);
    k_scan1<<<NC, THREADS, 0, stream>>>(cnt, ctot);
    k_scan2<<<1, THREADS, 0, stream>>>(ctot, counts, off_pad, cum_pad, npp, NC);
    k_eids<<<(nb + THREADS - 1) / THREADS, THREADS, 0, stream>>>(cum_pad, expert_ids, nb);
    k_gapfill<<<E + 64, THREADS, 0, stream>>>(counts, off_pad, cum_pad, sorted, M, T);
    k_scatter<<<G / WPB, THREADS, 0, stream>>>(topk, cnt, ctot, off_pad, sorted, sub);
}

// Round 3
// 57.839 us; speedup vs baseline: 1.6027x; 1.1086x over previous
//
#include <hip/hip_runtime.h>
#include <stdint.h>

#define NE 64        // real experts (ids in [0,64))
#define E  65        // num_experts + 1 (expert 64 always empty)
#define BLK 128      // block_size
#define WPB 4        // waves per 256-thread block
#define THREADS 256
#define SUBS 2048    // tokens per subchunk (one wave)
#define ITS  (SUBS / 64)   // 32
#define CHUNK 64     // subchunks per scan chunk
#define GV 4096      // subchunks total (T = GV * SUBS)
#define NC (GV / CHUNK)    // 64

// emulate match_any over 64 lanes for expert ids in [0,64): 6 ballots
__device__ __forceinline__ unsigned long long match_any6(int e) {
    unsigned long long m = ~0ull;
#pragma unroll
    for (int b = 0; b < 6; ++b) {
        unsigned long long bal = __ballot((e >> b) & 1);
        m &= ((e >> b) & 1) ? bal : ~bal;
    }
    return m;
}

// per-wave histogram via LDS atomics -> cnt[g][NE]
__global__ void __launch_bounds__(THREADS) k_hist(const int* __restrict__ topk,
                                                  int* __restrict__ cnt) {
    __shared__ int hist[WPB][NE];
    const int tid = threadIdx.x, w = tid >> 6, lane = tid & 63;
    const int g = blockIdx.x * WPB + w;
    hist[w][lane] = 0;                                   // wave-private row
    const int start = g * SUBS;
#pragma unroll
    for (int it = 0; it < SUBS / 256; ++it) {            // 8 iters, 256 tokens each
        int4 v = *(const int4*)(topk + start + it * 256 + lane * 4);
        atomicAdd(&hist[w][v.x], 1);
        atomicAdd(&hist[w][v.y], 1);
        atomicAdd(&hist[w][v.z], 1);
        atomicAdd(&hist[w][v.w], 1);
    }
    cnt[g * NE + lane] = hist[w][lane];
}

// level-1: exclusive scan over the 64 subchunks of each chunk (in place);
// chunk totals -> ctot[c][NE]
__global__ void k_scan1(int* __restrict__ cnt, int* __restrict__ ctot) {
    __shared__ int buf[CHUNK * NE];
    const int c = blockIdx.x, tid = threadIdx.x;
    for (int i = tid; i < CHUNK * NE; i += THREADS) buf[i] = cnt[c * CHUNK * NE + i];
    __syncthreads();
    if (tid < NE) {
        int acc = 0;
#pragma unroll 8
        for (int j = 0; j < CHUNK; ++j) {
            int old = buf[j * NE + tid];
            buf[j * NE + tid] = acc;
            acc += old;
        }
        ctot[c * NE + tid] = acc;
    }
    __syncthreads();
    for (int i = tid; i < CHUNK * NE; i += THREADS) cnt[c * CHUNK * NE + i] = buf[i];
}

// level-2: exclusive scan of ctot over chunks, per-expert totals,
// then off_pad / cum_pad / num_tokens_post_pad
__global__ void k_scan2(int* __restrict__ ctot, int* __restrict__ counts,
                        int* __restrict__ off_pad, int* __restrict__ cum_pad,
                        int* __restrict__ npp) {
    __shared__ int buf[NC * NE];
    const int tid = threadIdx.x;
    for (int i = tid; i < NC * NE; i += THREADS) buf[i] = ctot[i];
    __syncthreads();
    if (tid < NE) {
        int acc = 0;
        for (int c = 0; c < NC; ++c) {
            int old = buf[c * NE + tid];
            buf[c * NE + tid] = acc;
            acc += old;
        }
        counts[tid] = acc;
    }
    if (tid == NE) counts[NE] = 0;           // expert 64 never occurs
    __syncthreads();
    for (int i = tid; i < NC * NE; i += THREADS) ctot[i] = buf[i];
    if (tid == 0) {
        int run = 0;
        for (int e = 0; e < E; ++e) {
            int p = (counts[e] + BLK - 1) & ~(BLK - 1);
            off_pad[e] = run;
            run += p;
            cum_pad[e] = run;
        }
        *npp = run;
    }
}

__global__ void k_eids(const int* __restrict__ cum_pad, int* __restrict__ eids, int nb) {
    __shared__ int cp[E];
    int tid = threadIdx.x;
    if (tid < E) cp[tid] = cum_pad[tid];
    __syncthreads();
    int b = blockIdx.x * THREADS + tid;
    if (b < nb) {
        int bstart = b * BLK;
        int r = 0;
        if (bstart < cp[E - 1]) {
            int lo = 0, hi = E;
            while (lo < hi) { int mid = (lo + hi) >> 1; if (cp[mid] <= bstart) lo = mid + 1; else hi = mid; }
            r = lo;
        }
        eids[b] = r;
    }
}

// fill only the pad slots (per-expert gap) and the tail beyond cum_pad[E-1]
__global__ void k_gapfill(const int* __restrict__ counts, const int* __restrict__ off_pad,
                          const int* __restrict__ cum_pad, int* __restrict__ sorted,
                          int m, int fillv) {
    const int b = blockIdx.x, tid = threadIdx.x;
    if (b < E) {
        int c = counts[b];
        int p = (c + BLK - 1) & ~(BLK - 1);
        int len = p - c;                      // <= 127
        if (tid < len) sorted[off_pad[b] + c + tid] = fillv;
    } else {
        int total = cum_pad[E - 1];
        int i = total + (b - E) * THREADS + tid;
        if (i < m) sorted[i] = fillv;
    }
}

// stable scatter with LDS staging: counting-sort each wave's 2048-token batch
// in LDS, then write out contiguous per-expert segments (~128B each).
// All state is wave-private -> zero __syncthreads.
__global__ void __launch_bounds__(THREADS) k_scatter(const int* __restrict__ topk,
                          const int* __restrict__ base,   // cnt: [GV][NE] excl within chunk
                          const int* __restrict__ ctot,   // [NC][NE] excl chunk prefix
                          const int* __restrict__ off_pad,
                          int* __restrict__ sorted) {
    __shared__ int lrun[WPB][NE];     // running local counters, then loc_off
    __shared__ int dbase[WPB][NE];    // global dest base minus loc_off
    __shared__ int sbuf[WPB][SUBS];   // locally sorted (expert<<12 | local_idx)
    const int tid = threadIdx.x, w = tid >> 6, lane = tid & 63;
    const int g = blockIdx.x * WPB + w;
    const int chunk = g >> 6;         // g / CHUNK
    lrun[w][lane] = 0;
    const int start = g * SUBS;
    const unsigned long long lt = (1ull << lane) - 1ull;

    // phase A: match-any ranks + running per-expert counters (wave-lockstep RMW)
    int packed[ITS];
#pragma unroll
    for (int it = 0; it < ITS; ++it) {
        int e = topk[start + it * 64 + lane];
        unsigned long long m = match_any6(e);
        int r = __popcll(m & lt);
        int b = lrun[w][e];                       // all group lanes read same b
        packed[it] = (e << 12) | (b + r);         // local rank fits 11 bits
        if ((m & lt) == 0ull) lrun[w][e] = b + __popcll(m);
    }

    // phase B: wave-wide exclusive scan of local histogram -> loc_off, dbase
    int c = lrun[w][lane];
    int incl = c;
#pragma unroll
    for (int d = 1; d < 64; d <<= 1) {
        int t = __shfl_up(incl, d);
        if (lane >= d) incl += t;
    }
    int loc = incl - c;
    dbase[w][lane] = off_pad[lane] + ctot[chunk * NE + lane] + base[g * NE + lane] - loc;
    lrun[w][lane] = loc;

    // phase C: place into LDS in sorted order
#pragma unroll
    for (int it = 0; it < ITS; ++it) {
        int e = packed[it] >> 12;
        int lr = packed[it] & 0xfff;
        sbuf[w][lrun[w][e] + lr] = (e << 12) | (it * 64 + lane);
    }

    // phase D: write out; consecutive lanes -> consecutive dests within segments
#pragma unroll
    for (int it = 0; it < ITS; ++it) {
        int j = it * 64 + lane;
        int p = sbuf[w][j];
        int e = p >> 12;
        sorted[dbase[w][e] + j] = start + (p & 0xfff);
    }
}

extern "C" void kernel_launch(void* const* d_in, const int* in_sizes, int n_in,
                              void* d_out, int out_size, void* d_ws, size_t ws_size,
                              hipStream_t stream) {
    const int* topk = (const int*)d_in[0];
    const int T = in_sizes[0];                       // 8388608 = GV * SUBS
    const int M = T + E * (BLK - 1);
    const int nb = M / BLK;

    int* out = (int*)d_out;
    int* sorted = out;
    int* expert_ids = out + M;
    int* npp = out + M + nb;

    int* cnt     = (int*)d_ws;                       // GV*NE
    int* ctot    = cnt + (size_t)GV * NE;            // NC*NE
    int* counts  = ctot + (size_t)NC * NE;           // E
    int* off_pad = counts + E;                       // E
    int* cum_pad = off_pad + E;                      // E

    k_hist<<<GV / WPB, THREADS, 0, stream>>>(topk, cnt);
    k_scan1<<<NC, THREADS, 0, stream>>>(cnt, ctot);
    k_scan2<<<1, THREADS, 0, stream>>>(ctot, counts, off_pad, cum_pad, npp);
    k_eids<<<(nb + THREADS - 1) / THREADS, THREADS, 0, stream>>>(cum_pad, expert_ids, nb);
    k_gapfill<<<E + 64, THREADS, 0, stream>>>(counts, off_pad, cum_pad, sorted, M, T);
    k_scatter<<<GV / WPB, THREADS, 0, stream>>>(topk, cnt, ctot, off_pad, sorted);
}

// Round 4
// 55.154 us; speedup vs baseline: 1.6807x; 1.0487x over previous
//
#include <hip/hip_runtime.h>
#include <stdint.h>

#define NE 64        // real experts (ids in [0,64))
#define E  65        // num_experts + 1 (expert 64 always empty)
#define BLK 128      // block_size
#define WPB 4        // waves per 256-thread block
#define THREADS 256
#define CHUNK 64     // subchunks per scan chunk

// emulate match_any over 64 lanes for expert ids in [0,64): 6 ballots
__device__ __forceinline__ unsigned long long match_any6(int e) {
    unsigned long long m = ~0ull;
#pragma unroll
    for (int b = 0; b < 6; ++b) {
        unsigned long long bal = __ballot((e >> b) & 1);
        m &= ((e >> b) & 1) ? bal : ~bal;
    }
    return m;
}

// per-wave histogram via LDS atomics -> cnt[g][NE]
template<int SUBS>
__global__ void __launch_bounds__(THREADS, 8) k_hist(const int* __restrict__ topk,
                                                     int* __restrict__ cnt) {
    __shared__ int hist[WPB][NE];
    const int tid = threadIdx.x, w = tid >> 6, lane = tid & 63;
    const int g = blockIdx.x * WPB + w;
    hist[w][lane] = 0;                                   // wave-private row
    const int start = g * SUBS;
#pragma unroll
    for (int it = 0; it < SUBS / 256; ++it) {
        int4 v = *(const int4*)(topk + start + it * 256 + lane * 4);
        atomicAdd(&hist[w][v.x], 1);
        atomicAdd(&hist[w][v.y], 1);
        atomicAdd(&hist[w][v.z], 1);
        atomicAdd(&hist[w][v.w], 1);
    }
    cnt[g * NE + lane] = hist[w][lane];
}

// level-1: exclusive scan over the CHUNK subchunks of each chunk (in place);
// chunk totals -> ctot[c][NE]
__global__ void k_scan1(int* __restrict__ cnt, int* __restrict__ ctot) {
    __shared__ int buf[CHUNK * NE];
    const int c = blockIdx.x, tid = threadIdx.x;
    for (int i = tid; i < CHUNK * NE; i += THREADS) buf[i] = cnt[c * CHUNK * NE + i];
    __syncthreads();
    if (tid < NE) {
        int acc = 0;
#pragma unroll 8
        for (int j = 0; j < CHUNK; ++j) {
            int old = buf[j * NE + tid];
            buf[j * NE + tid] = acc;
            acc += old;
        }
        ctot[c * NE + tid] = acc;
    }
    __syncthreads();
    for (int i = tid; i < CHUNK * NE; i += THREADS) cnt[c * CHUNK * NE + i] = buf[i];
}

// level-2: exclusive scan of ctot over chunks, per-expert totals,
// then off_pad / cum_pad / num_tokens_post_pad
__global__ void k_scan2(int* __restrict__ ctot, int* __restrict__ counts,
                        int* __restrict__ off_pad, int* __restrict__ cum_pad,
                        int* __restrict__ npp, int nc) {
    extern __shared__ int buf[];
    const int tid = threadIdx.x;
    for (int i = tid; i < nc * NE; i += THREADS) buf[i] = ctot[i];
    __syncthreads();
    if (tid < NE) {
        int acc = 0;
#pragma unroll 8
        for (int c = 0; c < nc; ++c) {
            int old = buf[c * NE + tid];
            buf[c * NE + tid] = acc;
            acc += old;
        }
        counts[tid] = acc;
    }
    if (tid == NE) counts[NE] = 0;           // expert 64 never occurs
    __syncthreads();
    for (int i = tid; i < nc * NE; i += THREADS) ctot[i] = buf[i];
    if (tid == 0) {
        int run = 0;
        for (int e = 0; e < E; ++e) {
            int p = (counts[e] + BLK - 1) & ~(BLK - 1);
            off_pad[e] = run;
            run += p;
            cum_pad[e] = run;
        }
        *npp = run;
    }
}

__global__ void k_eids(const int* __restrict__ cum_pad, int* __restrict__ eids, int nb) {
    __shared__ int cp[E];
    int tid = threadIdx.x;
    if (tid < E) cp[tid] = cum_pad[tid];
    __syncthreads();
    int b = blockIdx.x * THREADS + tid;
    if (b < nb) {
        int bstart = b * BLK;
        int r = 0;
        if (bstart < cp[E - 1]) {
            int lo = 0, hi = E;
            while (lo < hi) { int mid = (lo + hi) >> 1; if (cp[mid] <= bstart) lo = mid + 1; else hi = mid; }
            r = lo;
        }
        eids[b] = r;
    }
}

// fill only the pad slots (per-expert gap) and the tail beyond cum_pad[E-1]
__global__ void k_gapfill(const int* __restrict__ counts, const int* __restrict__ off_pad,
                          const int* __restrict__ cum_pad, int* __restrict__ sorted,
                          int m, int fillv) {
    const int b = blockIdx.x, tid = threadIdx.x;
    if (b < E) {
        int c = counts[b];
        int p = (c + BLK - 1) & ~(BLK - 1);
        int len = p - c;                      // <= 127
        if (tid < len) sorted[off_pad[b] + c + tid] = fillv;
    } else {
        int total = cum_pad[E - 1];
        int i = total + (b - E) * THREADS + tid;
        if (i < m) sorted[i] = fillv;
    }
}

// stable scatter with LDS staging; per-expert counters via pipelined ds_add_rtn
// (leader atomics, hardware-ordered within a wave => stable), loc/dbase held in
// registers (lane l owns expert l) and fetched with __shfl. Zero __syncthreads.
template<int SUBS>
__global__ void __launch_bounds__(THREADS, SUBS == 1024 ? 8 : 4)
k_scatter(const int* __restrict__ topk,
          const int* __restrict__ base,   // cnt: [G][NE] excl within chunk
          const int* __restrict__ ctot,   // [NC][NE] excl chunk prefix
          const int* __restrict__ off_pad,
          int* __restrict__ sorted) {
    constexpr int ITS = SUBS / 64;
    constexpr int RSH = (SUBS == 1024) ? 10 : 11;   // bits for local idx/rank
    __shared__ int lrun[WPB][NE];     // running per-expert counters
    __shared__ int sbuf[WPB][SUBS];   // locally sorted (e<<RSH | local_idx)
    const int tid = threadIdx.x, w = tid >> 6, lane = tid & 63;
    const int g = blockIdx.x * WPB + w;
    const int chunk = g / CHUNK;
    lrun[w][lane] = 0;
    const int start = g * SUBS;
    const unsigned long long lt = (1ull << lane) - 1ull;

    // phase A: stable local ranks; leader-aggregated atomicAdd returns base.
    // Atomics from one wave are issued in program order -> ordered per address,
    // so no register-dependency chain across iterations.
    int packed[ITS];
#pragma unroll
    for (int it = 0; it < ITS; ++it) {
        int e = topk[start + it * 64 + lane];
        unsigned long long m = match_any6(e);
        int leader = (int)(__ffsll((long long)m) - 1);
        int r = __popcll(m & lt);
        int old_l = 0;
        if (lane == leader) old_l = atomicAdd(&lrun[w][e], __popcll(m));
        int b = __shfl(old_l, leader);
        packed[it] = (e << RSH) | (b + r);
    }

    // phase B: wave-wide exclusive scan of local histogram (registers only)
    int c = lrun[w][lane];            // lane owns expert `lane`
    int incl = c;
#pragma unroll
    for (int d = 1; d < 64; d <<= 1) {
        int t = __shfl_up(incl, d);
        if (lane >= d) incl += t;
    }
    int loc = incl - c;               // local segment start for expert `lane`
    int seg = off_pad[lane] + ctot[chunk * NE + lane] + base[g * NE + lane];
    int dbase = seg - loc;            // dest = j + dbase[e]

    // phase C: place token local-indices into LDS in sorted order
#pragma unroll
    for (int it = 0; it < ITS; ++it) {
        int e = packed[it] >> RSH;
        int lr = packed[it] & ((1 << RSH) - 1);
        int pos = __shfl(loc, e) + lr;
        sbuf[w][pos] = (e << RSH) | (it * 64 + lane);
    }

    // phase D: sequential LDS read, segmented-contiguous global write
#pragma unroll
    for (int it = 0; it < ITS; ++it) {
        int j = it * 64 + lane;
        int p = sbuf[w][j];
        int e = p >> RSH;
        int d = __shfl(dbase, e);
        sorted[d + j] = start + (p & ((1 << RSH) - 1));
    }
}

extern "C" void kernel_launch(void* const* d_in, const int* in_sizes, int n_in,
                              void* d_out, int out_size, void* d_ws, size_t ws_size,
                              hipStream_t stream) {
    const int* topk = (const int*)d_in[0];
    const int T = in_sizes[0];                       // 8388608
    const int M = T + E * (BLK - 1);
    const int nb = M / BLK;

    int* out = (int*)d_out;
    int* sorted = out;
    int* expert_ids = out + M;
    int* npp = out + M + nb;

    // prefer SUBS=1024 (G=8192) if workspace allows
    int SUBS = 1024;
    int G = T / SUBS;
    size_t need = ((size_t)G * NE + (size_t)(G / CHUNK) * NE + 3 * E) * sizeof(int);
    if (need > ws_size) { SUBS = 2048; G = T / SUBS; }
    const int NC = G / CHUNK;

    int* cnt     = (int*)d_ws;                       // G*NE
    int* ctot    = cnt + (size_t)G * NE;             // NC*NE
    int* counts  = ctot + (size_t)NC * NE;           // E
    int* off_pad = counts + E;                       // E
    int* cum_pad = off_pad + E;                      // E

    if (SUBS == 1024) {
        k_hist<1024><<<G / WPB, THREADS, 0, stream>>>(topk, cnt);
    } else {
        k_hist<2048><<<G / WPB, THREADS, 0, stream>>>(topk, cnt);
    }
    k_scan1<<<NC, THREADS, 0, stream>>>(cnt, ctot);
    k_scan2<<<1, THREADS, NC * NE * sizeof(int), stream>>>(ctot, counts, off_pad, cum_pad, npp, NC);
    k_eids<<<(nb + THREADS - 1) / THREADS, THREADS, 0, stream>>>(cum_pad, expert_ids, nb);
    k_gapfill<<<E + 64, THREADS, 0, stream>>>(counts, off_pad, cum_pad, sorted, M, T);
    if (SUBS == 1024) {
        k_scatter<1024><<<G / WPB, THREADS, 0, stream>>>(topk, cnt, ctot, off_pad, sorted);
    } else {
        k_scatter<2048><<<G / WPB, THREADS, 0, stream>>>(topk, cnt, ctot, off_pad, sorted);
    }
}

// Round 5
// 52.204 us; speedup vs baseline: 1.7757x; 1.0565x over previous
//
#include <hip/hip_runtime.h>
#include <stdint.h>

#define NE 64        // real experts (ids in [0,64))
#define E  65        // num_experts + 1 (expert 64 always empty)
#define BLK 128      // block_size
#define WPB 4        // waves per 256-thread block
#define THREADS 256
#define CHUNK 64     // subchunks per scan chunk

// emulate match_any over 64 lanes for expert ids in [0,64): 6 ballots
__device__ __forceinline__ unsigned long long match_any6(int e) {
    unsigned long long m = ~0ull;
#pragma unroll
    for (int b = 0; b < 6; ++b) {
        unsigned long long bal = __ballot((e >> b) & 1);
        m &= ((e >> b) & 1) ? bal : ~bal;
    }
    return m;
}

// ---------------- fast path: rank once, scatter from packed u16 ----------------

// per-wave stable ranks + wave hist; packed[(g*512)+q*64+lane] =
// (p(2q)<<16)|p(2q+1) with p(it) = (e<<10)|rank for token g*1024+it*64+lane
__global__ void __launch_bounds__(THREADS) k_rank(const int* __restrict__ topk,
                                                  uint32_t* __restrict__ packed,
                                                  int* __restrict__ cnt,
                                                  int* __restrict__ bcnt) {
    __shared__ int hist[WPB][NE];
    const int tid = threadIdx.x, w = tid >> 6, lane = tid & 63;
    const int g = blockIdx.x * WPB + w;
    hist[w][lane] = 0;                       // lane == expert, wave-private row
    const int start = g * 1024;
    const unsigned long long lt = (1ull << lane) - 1ull;
    uint32_t pk[8];
#pragma unroll
    for (int it = 0; it < 16; ++it) {
        int e = topk[start + it * 64 + lane];
        unsigned long long m = match_any6(e);
        int leader = (int)(__ffsll((long long)m) - 1);
        int r = __popcll(m & lt);
        int old_l = 0;
        if (lane == leader) old_l = atomicAdd(&hist[w][e], __popcll(m));
        int b = __shfl(old_l, leader);       // in-wave atomics are program-ordered
        uint32_t p = ((uint32_t)e << 10) | (uint32_t)(b + r);
        if (it & 1) pk[it >> 1] |= p; else pk[it >> 1] = p << 16;
    }
#pragma unroll
    for (int q = 0; q < 8; ++q)
        packed[(size_t)g * 512 + q * 64 + lane] = pk[q];
    cnt[g * NE + lane] = hist[w][lane];
    __syncthreads();
    if (w == 0)
        bcnt[blockIdx.x * NE + lane] =
            hist[0][lane] + hist[1][lane] + hist[2][lane] + hist[3][lane];
}

// block-level staged scatter: 4096 tokens sorted in LDS, contiguous write-out
__global__ void __launch_bounds__(THREADS) k_scat2(const uint32_t* __restrict__ packed,
                          const int* __restrict__ cnt,    // [G][NE] excl within chunk
                          const int* __restrict__ bcnt,   // [NB][NE] block totals
                          const int* __restrict__ ctot,   // [NC][NE] excl chunk prefix
                          const int* __restrict__ off_pad,
                          int* __restrict__ sorted) {
    __shared__ int sbuf[4096];
    const int tid = threadIdx.x, w = tid >> 6, lane = tid & 63;
    const int b = blockIdx.x, g0 = b * WPB, g = g0 + w;
    const int chunk = g0 / CHUNK;            // whole block is inside one chunk

    // lane owns expert `lane`
    int bc = bcnt[b * NE + lane];
    int incl = bc;
#pragma unroll
    for (int d = 1; d < 64; d <<= 1) {
        int t = __shfl_up(incl, d);
        if (lane >= d) incl += t;
    }
    int loc = incl - bc;                                  // sbuf segment start
    int base0 = cnt[g0 * NE + lane];
    int S = loc + (cnt[g * NE + lane] - base0);           // this wave's sbuf base
    int dbase = off_pad[lane] + ctot[chunk * NE + lane] + base0 - loc;

    // phase C: place block-local token indices into LDS in sorted order
    const int wbase = w * 1024;
#pragma unroll
    for (int q = 0; q < 8; ++q) {
        uint32_t pw = packed[(size_t)g * 512 + q * 64 + lane];
        int e0 = (int)(pw >> 26), r0 = (int)((pw >> 16) & 0x3ff);
        int e1 = (int)((pw >> 10) & 0x3f), r1 = (int)(pw & 0x3ff);
        int p0 = __shfl(S, e0) + r0;
        int p1 = __shfl(S, e1) + r1;
        sbuf[p0] = (e0 << 12) | (wbase + (2 * q) * 64 + lane);
        sbuf[p1] = (e1 << 12) | (wbase + (2 * q + 1) * 64 + lane);
    }
    __syncthreads();

    // phase D: sequential LDS read, segmented-contiguous global write
    const int bstart = b * 4096;
#pragma unroll
    for (int k = 0; k < 16; ++k) {
        int j = k * 256 + tid;
        int p = sbuf[j];
        int e = p >> 12;
        int d = __shfl(dbase, e);            // dbase identical across waves
        sorted[d + j] = bstart + (p & 0xfff);
    }
}

// ---------------- shared small kernels ----------------

// level-1: exclusive scan over the CHUNK subchunks of each chunk (in place);
// chunk totals -> ctot[c][NE]
__global__ void k_scan1(int* __restrict__ cnt, int* __restrict__ ctot) {
    __shared__ int buf[CHUNK * NE];
    const int c = blockIdx.x, tid = threadIdx.x;
    for (int i = tid; i < CHUNK * NE; i += THREADS) buf[i] = cnt[c * CHUNK * NE + i];
    __syncthreads();
    if (tid < NE) {
        int acc = 0;
#pragma unroll 8
        for (int j = 0; j < CHUNK; ++j) {
            int old = buf[j * NE + tid];
            buf[j * NE + tid] = acc;
            acc += old;
        }
        ctot[c * NE + tid] = acc;
    }
    __syncthreads();
    for (int i = tid; i < CHUNK * NE; i += THREADS) cnt[c * CHUNK * NE + i] = buf[i];
}

// level-2: scan of ctot over chunks; off_pad / cum_pad / num_tokens_post_pad
__global__ void k_scan2(int* __restrict__ ctot, int* __restrict__ counts,
                        int* __restrict__ off_pad, int* __restrict__ cum_pad,
                        int* __restrict__ npp, int nc) {
    extern __shared__ int buf[];
    const int tid = threadIdx.x;
    for (int i = tid; i < nc * NE; i += THREADS) buf[i] = ctot[i];
    __syncthreads();
    if (tid < NE) {
        int acc = 0;
#pragma unroll 8
        for (int c = 0; c < nc; ++c) {
            int old = buf[c * NE + tid];
            buf[c * NE + tid] = acc;
            acc += old;
        }
        counts[tid] = acc;
    }
    if (tid == NE) counts[NE] = 0;           // expert 64 never occurs
    __syncthreads();
    for (int i = tid; i < nc * NE; i += THREADS) ctot[i] = buf[i];
    if (tid == 0) {
        int run = 0;
        for (int e = 0; e < E; ++e) {
            int p = (counts[e] + BLK - 1) & ~(BLK - 1);
            off_pad[e] = run;
            run += p;
            cum_pad[e] = run;
        }
        *npp = run;
    }
}

__global__ void k_eids(const int* __restrict__ cum_pad, int* __restrict__ eids, int nb) {
    __shared__ int cp[E];
    int tid = threadIdx.x;
    if (tid < E) cp[tid] = cum_pad[tid];
    __syncthreads();
    int b = blockIdx.x * THREADS + tid;
    if (b < nb) {
        int bstart = b * BLK;
        int r = 0;
        if (bstart < cp[E - 1]) {
            int lo = 0, hi = E;
            while (lo < hi) { int mid = (lo + hi) >> 1; if (cp[mid] <= bstart) lo = mid + 1; else hi = mid; }
            r = lo;
        }
        eids[b] = r;
    }
}

// fill only the pad slots (per-expert gap) and the tail beyond cum_pad[E-1]
__global__ void k_gapfill(const int* __restrict__ counts, const int* __restrict__ off_pad,
                          const int* __restrict__ cum_pad, int* __restrict__ sorted,
                          int m, int fillv) {
    const int b = blockIdx.x, tid = threadIdx.x;
    if (b < E) {
        int c = counts[b];
        int p = (c + BLK - 1) & ~(BLK - 1);
        int len = p - c;                      // <= 127
        if (tid < len) sorted[off_pad[b] + c + tid] = fillv;
    } else {
        int total = cum_pad[E - 1];
        int i = total + (b - E) * THREADS + tid;
        if (i < m) sorted[i] = fillv;
    }
}

// ---------------- fallback path (R4) if workspace is small ----------------

template<int SUBS>
__global__ void __launch_bounds__(THREADS, 8) k_hist(const int* __restrict__ topk,
                                                     int* __restrict__ cnt) {
    __shared__ int hist[WPB][NE];
    const int tid = threadIdx.x, w = tid >> 6, lane = tid & 63;
    const int g = blockIdx.x * WPB + w;
    hist[w][lane] = 0;
    const int start = g * SUBS;
#pragma unroll
    for (int it = 0; it < SUBS / 256; ++it) {
        int4 v = *(const int4*)(topk + start + it * 256 + lane * 4);
        atomicAdd(&hist[w][v.x], 1);
        atomicAdd(&hist[w][v.y], 1);
        atomicAdd(&hist[w][v.z], 1);
        atomicAdd(&hist[w][v.w], 1);
    }
    cnt[g * NE + lane] = hist[w][lane];
}

template<int SUBS>
__global__ void __launch_bounds__(THREADS, SUBS == 1024 ? 8 : 4)
k_scatter(const int* __restrict__ topk, const int* __restrict__ base,
          const int* __restrict__ ctot, const int* __restrict__ off_pad,
          int* __restrict__ sorted) {
    constexpr int ITS = SUBS / 64;
    constexpr int RSH = (SUBS == 1024) ? 10 : 11;
    __shared__ int lrun[WPB][NE];
    __shared__ int sbuf[WPB][SUBS];
    const int tid = threadIdx.x, w = tid >> 6, lane = tid & 63;
    const int g = blockIdx.x * WPB + w;
    const int chunk = g / CHUNK;
    lrun[w][lane] = 0;
    const int start = g * SUBS;
    const unsigned long long lt = (1ull << lane) - 1ull;
    int packed[ITS];
#pragma unroll
    for (int it = 0; it < ITS; ++it) {
        int e = topk[start + it * 64 + lane];
        unsigned long long m = match_any6(e);
        int leader = (int)(__ffsll((long long)m) - 1);
        int r = __popcll(m & lt);
        int old_l = 0;
        if (lane == leader) old_l = atomicAdd(&lrun[w][e], __popcll(m));
        int b = __shfl(old_l, leader);
        packed[it] = (e << RSH) | (b + r);
    }
    int c = lrun[w][lane];
    int incl = c;
#pragma unroll
    for (int d = 1; d < 64; d <<= 1) {
        int t = __shfl_up(incl, d);
        if (lane >= d) incl += t;
    }
    int loc = incl - c;
    int seg = off_pad[lane] + ctot[chunk * NE + lane] + base[g * NE + lane];
    int dbase = seg - loc;
#pragma unroll
    for (int it = 0; it < ITS; ++it) {
        int e = packed[it] >> RSH;
        int lr = packed[it] & ((1 << RSH) - 1);
        int pos = __shfl(loc, e) + lr;
        sbuf[w][pos] = (e << RSH) | (it * 64 + lane);
    }
#pragma unroll
    for (int it = 0; it < ITS; ++it) {
        int j = it * 64 + lane;
        int p = sbuf[w][j];
        int e = p >> RSH;
        int d = __shfl(dbase, e);
        sorted[d + j] = start + (p & ((1 << RSH) - 1));
    }
}

extern "C" void kernel_launch(void* const* d_in, const int* in_sizes, int n_in,
                              void* d_out, int out_size, void* d_ws, size_t ws_size,
                              hipStream_t stream) {
    const int* topk = (const int*)d_in[0];
    const int T = in_sizes[0];                       // 8388608
    const int M = T + E * (BLK - 1);
    const int nb = M / BLK;

    int* out = (int*)d_out;
    int* sorted = out;
    int* expert_ids = out + M;
    int* npp = out + M + nb;

    const int G = T / 1024;                          // 8192 wave-subchunks
    const int NB = G / WPB;                          // 2048 blocks
    const int NC = G / CHUNK;                        // 128 chunks

    size_t need_fast = ((size_t)G * NE + (size_t)NC * NE + 3 * E + (size_t)NB * NE) * sizeof(int)
                     + (size_t)(T / 2) * sizeof(uint32_t);

    int* cnt     = (int*)d_ws;                       // G*NE
    int* ctot    = cnt + (size_t)G * NE;             // NC*NE
    int* counts  = ctot + (size_t)NC * NE;           // E
    int* off_pad = counts + E;                       // E
    int* cum_pad = off_pad + E;                      // E

    if (need_fast <= ws_size) {
        int* bcnt = cum_pad + E;                     // NB*NE
        uint32_t* packed = (uint32_t*)(bcnt + (size_t)NB * NE);   // T/2

        k_rank<<<NB, THREADS, 0, stream>>>(topk, packed, cnt, bcnt);
        k_scan1<<<NC, THREADS, 0, stream>>>(cnt, ctot);
        k_scan2<<<1, THREADS, NC * NE * sizeof(int), stream>>>(ctot, counts, off_pad, cum_pad, npp, NC);
        k_eids<<<(nb + THREADS - 1) / THREADS, THREADS, 0, stream>>>(cum_pad, expert_ids, nb);
        k_gapfill<<<E + 64, THREADS, 0, stream>>>(counts, off_pad, cum_pad, sorted, M, T);
        k_scat2<<<NB, THREADS, 0, stream>>>(packed, cnt, bcnt, ctot, off_pad, sorted);
    } else {
        // fallback (R4 structure), SUBS chosen to fit
        int SUBS = 1024, Gf = T / SUBS;
        size_t need = ((size_t)Gf * NE + (size_t)(Gf / CHUNK) * NE + 3 * E) * sizeof(int);
        if (need > ws_size) { SUBS = 2048; Gf = T / SUBS; }
        const int NCf = Gf / CHUNK;
        int* ctotf    = cnt + (size_t)Gf * NE;
        int* countsf  = ctotf + (size_t)NCf * NE;
        int* off_padf = countsf + E;
        int* cum_padf = off_padf + E;
        if (SUBS == 1024) k_hist<1024><<<Gf / WPB, THREADS, 0, stream>>>(topk, cnt);
        else              k_hist<2048><<<Gf / WPB, THREADS, 0, stream>>>(topk, cnt);
        k_scan1<<<NCf, THREADS, 0, stream>>>(cnt, ctotf);
        k_scan2<<<1, THREADS, NCf * NE * sizeof(int), stream>>>(ctotf, countsf, off_padf, cum_padf, npp, NCf);
        k_eids<<<(nb + THREADS - 1) / THREADS, THREADS, 0, stream>>>(cum_padf, expert_ids, nb);
        k_gapfill<<<E + 64, THREADS, 0, stream>>>(countsf, off_padf, cum_padf, sorted, M, T);
        if (SUBS == 1024) k_scatter<1024><<<Gf / WPB, THREADS, 0, stream>>>(topk, cnt, ctotf, off_padf, sorted);
        else              k_scatter<2048><<<Gf / WPB, THREADS, 0, stream>>>(topk, cnt, ctotf, off_padf, sorted);
    }
}